// Round 1
// baseline (1197.320 us; speedup 1.0000x reference)
//
#include <hip/hip_runtime.h>
#include <hip/hip_bf16.h>
#include <math.h>

// ---------------------------------------------------------------------------
// GAT 2-layer + classifier, fp32. One wave (64 lanes) per node for
// attention aggregation with online softmax; CSR built per call.
// ---------------------------------------------------------------------------

__global__ __launch_bounds__(256) void count_kernel(const int* __restrict__ dst,
                                                    int* __restrict__ cnt, int E) {
  int e = blockIdx.x * 256 + threadIdx.x;
  if (e < E) atomicAdd(&cnt[dst[e]], 1);
}

__global__ __launch_bounds__(1024) void scan_kernel(const int* __restrict__ cnt,
                                                    int* __restrict__ offs,
                                                    int* __restrict__ wpos, int n) {
  __shared__ int buf[1024];
  __shared__ int carry_s;
  if (threadIdx.x == 0) { carry_s = 0; offs[0] = 0; }
  __syncthreads();
  for (int base = 0; base < n; base += 1024) {
    int i = base + (int)threadIdx.x;
    int v = (i < n) ? cnt[i] : 0;
    buf[threadIdx.x] = v;
    __syncthreads();
    for (int off = 1; off < 1024; off <<= 1) {
      int t = (threadIdx.x >= (unsigned)off) ? buf[threadIdx.x - off] : 0;
      __syncthreads();
      buf[threadIdx.x] += t;
      __syncthreads();
    }
    int incl = buf[threadIdx.x] + carry_s;
    if (i < n) { offs[i + 1] = incl; wpos[i] = incl - v; }
    __syncthreads();
    if (threadIdx.x == 1023) carry_s = incl;
    __syncthreads();
  }
}

__global__ __launch_bounds__(256) void fill_kernel(const int* __restrict__ dst,
                                                   int* __restrict__ wpos,
                                                   int* __restrict__ elist, int E) {
  int e = blockIdx.x * 256 + threadIdx.x;
  if (e < E) {
    int p = atomicAdd(&wpos[dst[e]], 1);
    elist[p] = e;
  }
}

// Wa[layer][h][d] = sum_c ae[h][c] * We[h*32+c][d]   (two layers, 128 threads)
__global__ __launch_bounds__(128) void wa_kernel(const float* __restrict__ ae1,
                                                 const float* __restrict__ We1,
                                                 const float* __restrict__ ae2,
                                                 const float* __restrict__ We2,
                                                 float* __restrict__ Wa) {
  int t = threadIdx.x;
  const float* ae = (t < 64) ? ae1 : ae2;
  const float* We = (t < 64) ? We1 : We2;
  int h = (t >> 4) & 3;
  int d = t & 15;
  float s = 0.f;
  for (int c = 0; c < 32; ++c) s += ae[h * 32 + c] * We[(h * 32 + c) * 16 + d];
  Wa[t] = s;
}

// alpha_e[e][h] = ea[e][:] . Wa[h][:]
__global__ __launch_bounds__(256) void alphae_kernel(const float* __restrict__ ea,
                                                     const float* __restrict__ Wa,
                                                     float* __restrict__ aeE, int E) {
  __shared__ float wa[64];
  if (threadIdx.x < 64) wa[threadIdx.x] = Wa[threadIdx.x];
  __syncthreads();
  int e = blockIdx.x * 256 + threadIdx.x;
  if (e >= E) return;
  const float4* p = (const float4*)(ea + (size_t)e * 16);
  float4 q0 = p[0], q1 = p[1], q2 = p[2], q3 = p[3];
  float v[16] = {q0.x, q0.y, q0.z, q0.w, q1.x, q1.y, q1.z, q1.w,
                 q2.x, q2.y, q2.z, q2.w, q3.x, q3.y, q3.z, q3.w};
  float rr[4];
#pragma unroll
  for (int h = 0; h < 4; ++h) {
    float s = 0.f;
#pragma unroll
    for (int d = 0; d < 16; ++d) s += v[d] * wa[h * 16 + d];
    rr[h] = s;
  }
  *(float4*)(aeE + (size_t)e * 4) = make_float4(rr[0], rr[1], rr[2], rr[3]);
}

// H[n][o] = sum_k X[n][k] * W[o][k];  tile 64 nodes x 128 outs, Kc = 32
__global__ __launch_bounds__(256) void gemm_kernel(const float* __restrict__ X,
                                                   const float* __restrict__ W,
                                                   float* __restrict__ H,
                                                   int n, int K) {
  __shared__ float xs[64 * 36];
  __shared__ float wsm[128 * 36];
  const int tx = threadIdx.x & 15;
  const int ty = threadIdx.x >> 4;
  const int n0 = blockIdx.x * 64;
  float acc[4][8];
#pragma unroll
  for (int i = 0; i < 4; ++i)
#pragma unroll
    for (int j = 0; j < 8; ++j) acc[i][j] = 0.f;

  for (int k0 = 0; k0 < K; k0 += 32) {
    for (int f = threadIdx.x; f < 512; f += 256) {
      int r = f >> 3, c4 = (f & 7) << 2;
      int row = n0 + r;
      float4 v = make_float4(0.f, 0.f, 0.f, 0.f);
      if (row < n) v = *(const float4*)(X + (size_t)row * K + k0 + c4);
      *(float4*)(xs + r * 36 + c4) = v;
    }
    for (int f = threadIdx.x; f < 1024; f += 256) {
      int r = f >> 3, c4 = (f & 7) << 2;
      float4 v = *(const float4*)(W + (size_t)r * K + k0 + c4);
      *(float4*)(wsm + r * 36 + c4) = v;
    }
    __syncthreads();
#pragma unroll
    for (int k4 = 0; k4 < 8; ++k4) {
      float4 xr[4], wr[8];
#pragma unroll
      for (int i = 0; i < 4; ++i) xr[i] = *(const float4*)(xs + (ty + 16 * i) * 36 + k4 * 4);
#pragma unroll
      for (int j = 0; j < 8; ++j) wr[j] = *(const float4*)(wsm + (tx + 16 * j) * 36 + k4 * 4);
#pragma unroll
      for (int i = 0; i < 4; ++i)
#pragma unroll
        for (int j = 0; j < 8; ++j)
          acc[i][j] += xr[i].x * wr[j].x + xr[i].y * wr[j].y +
                       xr[i].z * wr[j].z + xr[i].w * wr[j].w;
    }
    __syncthreads();
  }
#pragma unroll
  for (int i = 0; i < 4; ++i) {
    int row = n0 + ty + 16 * i;
    if (row < n) {
#pragma unroll
      for (int j = 0; j < 8; ++j)
        H[(size_t)row * 128 + tx + 16 * j] = acc[i][j];
    }
  }
}

// per-node head scores: ssc[n][h] = sum_c h[n][h*32+c]*a_s[h][c]; same for a_d
__global__ __launch_bounds__(256) void score_kernel(const float* __restrict__ h,
                                                    const float* __restrict__ a_s,
                                                    const float* __restrict__ a_d,
                                                    float* __restrict__ ssc,
                                                    float* __restrict__ dsc, int n) {
  int gid = blockIdx.x * 256 + threadIdx.x;
  int node = gid >> 6;
  int lane = threadIdx.x & 63;
  if (node >= n) return;
  int ch = lane * 2;
  float2 hv = *(const float2*)(h + (size_t)node * 128 + ch);
  float ps = hv.x * a_s[ch] + hv.y * a_s[ch + 1];
  float pd = hv.x * a_d[ch] + hv.y * a_d[ch + 1];
#pragma unroll
  for (int off = 8; off; off >>= 1) {
    ps += __shfl_xor(ps, off, 16);
    pd += __shfl_xor(pd, off, 16);
  }
  if ((lane & 15) == 0) {
    int head = lane >> 4;
    ssc[node * 4 + head] = ps;
    dsc[node * 4 + head] = pd;
  }
}

__device__ __forceinline__ float leaky02(float a) { return a > 0.f ? a : 0.2f * a; }

// one wave per node: online-softmax attention aggregation + bias + relu
__global__ __launch_bounds__(256) void agg_kernel(const float* __restrict__ hin,
                                                  const float* __restrict__ ssc,
                                                  const float* __restrict__ dsc,
                                                  const float* __restrict__ aeE,
                                                  const int* __restrict__ offs,
                                                  const int* __restrict__ elist,
                                                  const int* __restrict__ src,
                                                  const float* __restrict__ bias,
                                                  float* __restrict__ hout, int n) {
  int wave = (blockIdx.x * 256 + threadIdx.x) >> 6;
  int lane = threadIdx.x & 63;
  if (wave >= n) return;
  const int node = wave;
  const int head = lane >> 4;
  const int ch = lane * 2;
  const float dscv = dsc[node * 4 + head];
  const int j0 = offs[node], j1 = offs[node + 1];
  float m = -INFINITY, lsum = 0.f, acc0 = 0.f, acc1 = 0.f, sum_ae = 0.f;
  for (int j = j0; j < j1; ++j) {
    int e = elist[j];
    int s = src[e];
    float a_e = aeE[(size_t)e * 4 + head];
    sum_ae += a_e;
    float a = leaky02(ssc[s * 4 + head] + dscv + a_e);
    float mn = fmaxf(m, a);
    float sc = __expf(m - mn);
    float p = __expf(a - mn);
    float2 hv = *(const float2*)(hin + (size_t)s * 128 + ch);
    lsum = lsum * sc + p;
    acc0 = acc0 * sc + p * hv.x;
    acc1 = acc1 * sc + p * hv.y;
    m = mn;
  }
  // self loop: edge feature = mean of incoming raw alpha_e
  int deg = j1 - j0;
  float a_loop = leaky02(ssc[node * 4 + head] + dscv + sum_ae / fmaxf((float)deg, 1.f));
  float mn = fmaxf(m, a_loop);
  float sc = __expf(m - mn);
  float p = __expf(a_loop - mn);
  float2 hv = *(const float2*)(hin + (size_t)node * 128 + ch);
  lsum = lsum * sc + p;
  acc0 = acc0 * sc + p * hv.x;
  acc1 = acc1 * sc + p * hv.y;
  float inv = 1.f / (lsum + 1e-16f);
  float o0 = acc0 * inv + bias[ch];
  float o1 = acc1 * inv + bias[ch + 1];
  hout[(size_t)node * 128 + ch] = fmaxf(o0, 0.f);
  hout[(size_t)node * 128 + ch + 1] = fmaxf(o1, 0.f);
}

// logits = h @ Wlin.T + blin; log_softmax over 40 classes. one wave per node.
__global__ __launch_bounds__(256) void classifier_kernel(const float* __restrict__ h,
                                                         const float* __restrict__ Wlin,
                                                         const float* __restrict__ blin,
                                                         float* __restrict__ out, int n) {
  __shared__ float wt[128 * 40];
  __shared__ float hs[4][128];
  for (int idx = threadIdx.x; idx < 40 * 128; idx += 256) {
    int c = idx >> 7, k = idx & 127;
    wt[k * 40 + c] = Wlin[idx];
  }
  int w = threadIdx.x >> 6, lane = threadIdx.x & 63;
  int node = blockIdx.x * 4 + w;
  if (node < n) {
    hs[w][lane] = h[(size_t)node * 128 + lane];
    hs[w][lane + 64] = h[(size_t)node * 128 + lane + 64];
  }
  __syncthreads();
  if (node >= n) return;
  float logit = -INFINITY;
  if (lane < 40) {
    float acc = blin[lane];
#pragma unroll 4
    for (int k = 0; k < 128; ++k) acc += hs[w][k] * wt[k * 40 + lane];
    logit = acc;
  }
  float mx = logit;
#pragma unroll
  for (int off = 32; off; off >>= 1) mx = fmaxf(mx, __shfl_xor(mx, off));
  float ex = (lane < 40) ? __expf(logit - mx) : 0.f;
  float sm = ex;
#pragma unroll
  for (int off = 32; off; off >>= 1) sm += __shfl_xor(sm, off);
  if (lane < 40) out[(size_t)node * 40 + lane] = logit - mx - __logf(sm);
}

extern "C" void kernel_launch(void* const* d_in, const int* in_sizes, int n_in,
                              void* d_out, int out_size, void* d_ws, size_t ws_size,
                              hipStream_t stream) {
  const float* x    = (const float*)d_in[0];
  const int*   eidx = (const int*)d_in[1];
  const float* ea   = (const float*)d_in[2];
  const float* W1   = (const float*)d_in[3];
  const float* as1  = (const float*)d_in[4];
  const float* ad1  = (const float*)d_in[5];
  const float* ae1w = (const float*)d_in[6];
  const float* We1  = (const float*)d_in[7];
  const float* b1   = (const float*)d_in[8];
  const float* W2   = (const float*)d_in[9];
  const float* as2  = (const float*)d_in[10];
  const float* ad2  = (const float*)d_in[11];
  const float* ae2w = (const float*)d_in[12];
  const float* We2  = (const float*)d_in[13];
  const float* b2   = (const float*)d_in[14];
  const float* Wlin = (const float*)d_in[15];
  const float* blin = (const float*)d_in[16];
  float* out = (float*)d_out;

  const int N = in_sizes[0] / 64;
  const int E = in_sizes[1] / 2;
  const int* src = eidx;
  const int* dst = eidx + E;

  char* wsb = (char*)d_ws;
  size_t off = 0;
  auto alloc = [&](size_t bytes) -> void* {
    void* p = wsb + off;
    off = (off + bytes + 255) & ~(size_t)255;
    return p;
  };
  int*   cnt   = (int*)alloc((size_t)N * 4);
  int*   offs  = (int*)alloc((size_t)(N + 1) * 4);
  int*   wpos  = (int*)alloc((size_t)N * 4);
  int*   elist = (int*)alloc((size_t)E * 4);
  float* Wa    = (float*)alloc(128 * 4);
  float* ssc   = (float*)alloc((size_t)N * 4 * 4);
  float* dsc   = (float*)alloc((size_t)N * 4 * 4);
  float* aeE   = (float*)alloc((size_t)E * 4 * 4);
  float* hA    = (float*)alloc((size_t)N * 128 * 4);
  float* hB    = (float*)alloc((size_t)N * 128 * 4);

  const int ge = (E + 255) / 256;
  const int gg = (N + 63) / 64;
  const int gn = (N + 3) / 4;

  hipMemsetAsync(cnt, 0, (size_t)N * 4, stream);
  count_kernel<<<ge, 256, 0, stream>>>(dst, cnt, E);
  scan_kernel<<<1, 1024, 0, stream>>>(cnt, offs, wpos, N);
  fill_kernel<<<ge, 256, 0, stream>>>(dst, wpos, elist, E);
  wa_kernel<<<1, 128, 0, stream>>>(ae1w, We1, ae2w, We2, Wa);

  // ---- layer 1 ----
  alphae_kernel<<<ge, 256, 0, stream>>>(ea, Wa, aeE, E);
  gemm_kernel<<<gg, 256, 0, stream>>>(x, W1, hA, N, 64);
  score_kernel<<<gn, 256, 0, stream>>>(hA, as1, ad1, ssc, dsc, N);
  agg_kernel<<<gn, 256, 0, stream>>>(hA, ssc, dsc, aeE, offs, elist, src, b1, hB, N);

  // ---- layer 2 ----
  alphae_kernel<<<ge, 256, 0, stream>>>(ea, Wa + 64, aeE, E);
  gemm_kernel<<<gg, 256, 0, stream>>>(hB, W2, hA, N, 128);
  score_kernel<<<gn, 256, 0, stream>>>(hA, as2, ad2, ssc, dsc, N);
  agg_kernel<<<gn, 256, 0, stream>>>(hA, ssc, dsc, aeE, offs, elist, src, b2, hB, N);

  // ---- classifier + log_softmax ----
  classifier_kernel<<<gn, 256, 0, stream>>>(hB, Wlin, blin, out, N);
}

// Round 3
// 848.032 us; speedup vs baseline: 1.4119x; 1.4119x over previous
//
#include <hip/hip_runtime.h>
#include <hip/hip_bf16.h>
#include <math.h>

// ---------------------------------------------------------------------------
// GAT 2-layer + classifier, fp32.
// R2: R1 structure (chunked two-phase agg, parallel scan) with workspace cut
//     to ~79 MB (< R0's proven-safe 85.4 MB): alpha_e stored bf16x4 in CSR
//     slot order (coalesced stream in agg; elist only used by alphae).
// ---------------------------------------------------------------------------

__device__ __forceinline__ unsigned short f2bf(float f) {
  unsigned u = __float_as_uint(f);
  unsigned r = u + 0x7FFFu + ((u >> 16) & 1u);
  return (unsigned short)(r >> 16);
}
__device__ __forceinline__ float bf2f(unsigned short b) {
  return __uint_as_float(((unsigned)b) << 16);
}

__global__ __launch_bounds__(256) void count_kernel(const int* __restrict__ dst,
                                                    int* __restrict__ cnt, int E) {
  int e = blockIdx.x * 256 + threadIdx.x;
  if (e < E) atomicAdd(&cnt[dst[e]], 1);
}

// local inclusive scan per 1024-block; block sums to bsum
__global__ __launch_bounds__(1024) void scan1_kernel(const int* __restrict__ cnt,
                                                     int* __restrict__ offs,
                                                     int* __restrict__ bsum, int n) {
  __shared__ int buf[1024];
  int i = blockIdx.x * 1024 + threadIdx.x;
  int v = (i < n) ? cnt[i] : 0;
  buf[threadIdx.x] = v;
  __syncthreads();
  for (int off = 1; off < 1024; off <<= 1) {
    int t = (threadIdx.x >= (unsigned)off) ? buf[threadIdx.x - off] : 0;
    __syncthreads();
    buf[threadIdx.x] += t;
    __syncthreads();
  }
  if (i < n) offs[i + 1] = buf[threadIdx.x];
  if (threadIdx.x == 1023) bsum[blockIdx.x] = buf[1023];
}

// inclusive scan of up to 64 block sums (one wave)
__global__ __launch_bounds__(64) void scan2_kernel(int* __restrict__ bsum, int nb) {
  int lane = threadIdx.x;
  int v = (lane < nb) ? bsum[lane] : 0;
#pragma unroll
  for (int off = 1; off < 64; off <<= 1) {
    int t = __shfl_up(v, off);
    if (lane >= off) v += t;
  }
  if (lane < nb) bsum[lane] = v;
}

__global__ __launch_bounds__(1024) void scan3_kernel(const int* __restrict__ cnt,
                                                     int* __restrict__ offs,
                                                     const int* __restrict__ bsum,
                                                     int* __restrict__ wpos, int n) {
  int i = blockIdx.x * 1024 + threadIdx.x;
  if (i >= n) return;
  int add = (blockIdx.x > 0) ? bsum[blockIdx.x - 1] : 0;
  int incl = offs[i + 1] + add;
  offs[i + 1] = incl;
  wpos[i] = incl - cnt[i];
  if (i == 0) offs[0] = 0;
}

__global__ __launch_bounds__(256) void fill_kernel(const int* __restrict__ src,
                                                   const int* __restrict__ dst,
                                                   int* __restrict__ wpos,
                                                   int* __restrict__ elist,
                                                   int* __restrict__ srcS, int E) {
  int e = blockIdx.x * 256 + threadIdx.x;
  if (e < E) {
    int p = atomicAdd(&wpos[dst[e]], 1);
    elist[p] = e;
    srcS[p] = src[e];
  }
}

// Wa[layer][h][d] = sum_c ae[h][c] * We[h*32+c][d]   (two layers, 128 threads)
__global__ __launch_bounds__(128) void wa_kernel(const float* __restrict__ ae1,
                                                 const float* __restrict__ We1,
                                                 const float* __restrict__ ae2,
                                                 const float* __restrict__ We2,
                                                 float* __restrict__ Wa) {
  int t = threadIdx.x;
  const float* ae = (t < 64) ? ae1 : ae2;
  const float* We = (t < 64) ? We1 : We2;
  int h = (t >> 4) & 3;
  int d = t & 15;
  float s = 0.f;
  for (int c = 0; c < 32; ++c) s += ae[h * 32 + c] * We[(h * 32 + c) * 16 + d];
  Wa[t] = s;
}

// CSR-ordered: slot j -> edge e=elist[j]; aeEb[j][h] = ea[e][:] . Wa[h][:]
// stored as bf16x4 (coalesced 8B/slot write; agg streams it back in order).
__global__ __launch_bounds__(256) void alphae_kernel(const int* __restrict__ elist,
                                                     const float* __restrict__ ea,
                                                     const float* __restrict__ Wa,
                                                     unsigned short* __restrict__ aeEb,
                                                     int E) {
  __shared__ float wa[64];
  if (threadIdx.x < 64) wa[threadIdx.x] = Wa[threadIdx.x];
  __syncthreads();
  int j = blockIdx.x * 256 + threadIdx.x;
  if (j >= E) return;
  const int e = elist[j];
  const float4* p = (const float4*)(ea + (size_t)e * 16);
  float4 q0 = p[0], q1 = p[1], q2 = p[2], q3 = p[3];
  float v[16] = {q0.x, q0.y, q0.z, q0.w, q1.x, q1.y, q1.z, q1.w,
                 q2.x, q2.y, q2.z, q2.w, q3.x, q3.y, q3.z, q3.w};
  unsigned short rr[4];
#pragma unroll
  for (int h = 0; h < 4; ++h) {
    float s = 0.f;
#pragma unroll
    for (int d = 0; d < 16; ++d) s += v[d] * wa[h * 16 + d];
    rr[h] = f2bf(s);
  }
  ushort4 o; o.x = rr[0]; o.y = rr[1]; o.z = rr[2]; o.w = rr[3];
  *(ushort4*)(aeEb + (size_t)j * 4) = o;
}

// H[n][o] = sum_k X[n][k] * W[o][k];  tile 64 nodes x 128 outs, Kc = 32
__global__ __launch_bounds__(256) void gemm_kernel(const float* __restrict__ X,
                                                   const float* __restrict__ W,
                                                   float* __restrict__ H,
                                                   int n, int K) {
  __shared__ float xs[64 * 36];
  __shared__ float wsm[128 * 36];
  const int tx = threadIdx.x & 15;
  const int ty = threadIdx.x >> 4;
  const int n0 = blockIdx.x * 64;
  float acc[4][8];
#pragma unroll
  for (int i = 0; i < 4; ++i)
#pragma unroll
    for (int j = 0; j < 8; ++j) acc[i][j] = 0.f;

  for (int k0 = 0; k0 < K; k0 += 32) {
    for (int f = threadIdx.x; f < 512; f += 256) {
      int r = f >> 3, c4 = (f & 7) << 2;
      int row = n0 + r;
      float4 v = make_float4(0.f, 0.f, 0.f, 0.f);
      if (row < n) v = *(const float4*)(X + (size_t)row * K + k0 + c4);
      *(float4*)(xs + r * 36 + c4) = v;
    }
    for (int f = threadIdx.x; f < 1024; f += 256) {
      int r = f >> 3, c4 = (f & 7) << 2;
      float4 v = *(const float4*)(W + (size_t)r * K + k0 + c4);
      *(float4*)(wsm + r * 36 + c4) = v;
    }
    __syncthreads();
#pragma unroll
    for (int k4 = 0; k4 < 8; ++k4) {
      float4 xr[4], wr[8];
#pragma unroll
      for (int i = 0; i < 4; ++i) xr[i] = *(const float4*)(xs + (ty + 16 * i) * 36 + k4 * 4);
#pragma unroll
      for (int j = 0; j < 8; ++j) wr[j] = *(const float4*)(wsm + (tx + 16 * j) * 36 + k4 * 4);
#pragma unroll
      for (int i = 0; i < 4; ++i)
#pragma unroll
        for (int j = 0; j < 8; ++j)
          acc[i][j] += xr[i].x * wr[j].x + xr[i].y * wr[j].y +
                       xr[i].z * wr[j].z + xr[i].w * wr[j].w;
    }
    __syncthreads();
  }
#pragma unroll
  for (int i = 0; i < 4; ++i) {
    int row = n0 + ty + 16 * i;
    if (row < n) {
#pragma unroll
      for (int j = 0; j < 8; ++j)
        H[(size_t)row * 128 + tx + 16 * j] = acc[i][j];
    }
  }
}

// per-node head scores: ssc[n][h] = sum_c h[n][h*32+c]*a_s[h][c]; same for a_d
__global__ __launch_bounds__(256) void score_kernel(const float* __restrict__ h,
                                                    const float* __restrict__ a_s,
                                                    const float* __restrict__ a_d,
                                                    float* __restrict__ ssc,
                                                    float* __restrict__ dsc, int n) {
  int gid = blockIdx.x * 256 + threadIdx.x;
  int node = gid >> 6;
  int lane = threadIdx.x & 63;
  if (node >= n) return;
  int ch = lane * 2;
  float2 hv = *(const float2*)(h + (size_t)node * 128 + ch);
  float ps = hv.x * a_s[ch] + hv.y * a_s[ch + 1];
  float pd = hv.x * a_d[ch] + hv.y * a_d[ch + 1];
#pragma unroll
  for (int off = 8; off; off >>= 1) {
    ps += __shfl_xor(ps, off, 16);
    pd += __shfl_xor(pd, off, 16);
  }
  if ((lane & 15) == 0) {
    int head = lane >> 4;
    ssc[node * 4 + head] = ps;
    dsc[node * 4 + head] = pd;
  }
}

__device__ __forceinline__ float leaky02(float a) { return a > 0.f ? a : 0.2f * a; }
__device__ __forceinline__ float sel4(float4 v, int h) {
  return (h == 0) ? v.x : (h == 1) ? v.y : (h == 2) ? v.z : v.w;
}

// one wave per node, chunked two-phase online-softmax aggregation.
// Phase A: 64 lanes gather metadata for 64 edges in parallel (srcS + aeEb
// streamed in CSR order, ssc gathered), compute logits/exps, stage in LDS.
// Phase B: pure p*hv accumulate. Per-wave LDS only (no __syncthreads).
__global__ __launch_bounds__(256) void agg_kernel(const float* __restrict__ hin,
                                                  const float* __restrict__ ssc,
                                                  const float* __restrict__ dsc,
                                                  const unsigned short* __restrict__ aeEb,
                                                  const int* __restrict__ offs,
                                                  const int* __restrict__ srcS,
                                                  const float* __restrict__ bias,
                                                  float* __restrict__ hout, int n) {
  __shared__ int sbuf[4][64];
  __shared__ float pbuf[4][64 * 4];
  const int wv = threadIdx.x >> 6;
  const int lane = threadIdx.x & 63;
  const int node = blockIdx.x * 4 + wv;
  if (node >= n) return;
  const int head = lane >> 4;
  const int ch = lane * 2;
  const float4 dv = *(const float4*)(dsc + (size_t)node * 4);
  float4 m4 = make_float4(-INFINITY, -INFINITY, -INFINITY, -INFINITY);
  float4 l4 = make_float4(0.f, 0.f, 0.f, 0.f);
  float4 sa = make_float4(0.f, 0.f, 0.f, 0.f);
  float acc0 = 0.f, acc1 = 0.f;
  const int j0 = offs[node], j1 = offs[node + 1];

  for (int jc = j0; jc < j1; jc += 64) {
    const int len = min(64, j1 - jc);
    float4 a4 = make_float4(-INFINITY, -INFINITY, -INFINITY, -INFINITY);
    int sv = 0;
    if (lane < len) {
      const int j = jc + lane;
      sv = srcS[j];
      const ushort4 aq = *(const ushort4*)(aeEb + (size_t)j * 4);
      const float4 ae4 = make_float4(bf2f(aq.x), bf2f(aq.y), bf2f(aq.z), bf2f(aq.w));
      const float4 ss4 = *(const float4*)(ssc + (size_t)sv * 4);
      sa.x += ae4.x; sa.y += ae4.y; sa.z += ae4.z; sa.w += ae4.w;
      a4.x = leaky02(ss4.x + dv.x + ae4.x);
      a4.y = leaky02(ss4.y + dv.y + ae4.y);
      a4.z = leaky02(ss4.z + dv.z + ae4.z);
      a4.w = leaky02(ss4.w + dv.w + ae4.w);
    }
    sbuf[wv][lane] = sv;
    // chunk max per head
    float4 cm = a4;
#pragma unroll
    for (int off = 32; off; off >>= 1) {
      cm.x = fmaxf(cm.x, __shfl_xor(cm.x, off));
      cm.y = fmaxf(cm.y, __shfl_xor(cm.y, off));
      cm.z = fmaxf(cm.z, __shfl_xor(cm.z, off));
      cm.w = fmaxf(cm.w, __shfl_xor(cm.w, off));
    }
    float4 mn = make_float4(fmaxf(m4.x, cm.x), fmaxf(m4.y, cm.y),
                            fmaxf(m4.z, cm.z), fmaxf(m4.w, cm.w));
    float4 p4;
    p4.x = (lane < len) ? __expf(a4.x - mn.x) : 0.f;
    p4.y = (lane < len) ? __expf(a4.y - mn.y) : 0.f;
    p4.z = (lane < len) ? __expf(a4.z - mn.z) : 0.f;
    p4.w = (lane < len) ? __expf(a4.w - mn.w) : 0.f;
    *(float4*)(&pbuf[wv][lane * 4]) = p4;
    // chunk sum of p per head
    float4 ps = p4;
#pragma unroll
    for (int off = 32; off; off >>= 1) {
      ps.x += __shfl_xor(ps.x, off);
      ps.y += __shfl_xor(ps.y, off);
      ps.z += __shfl_xor(ps.z, off);
      ps.w += __shfl_xor(ps.w, off);
    }
    float4 sc;
    sc.x = __expf(m4.x - mn.x);
    sc.y = __expf(m4.y - mn.y);
    sc.z = __expf(m4.z - mn.z);
    sc.w = __expf(m4.w - mn.w);
    const float sch = sel4(sc, head);
    acc0 *= sch; acc1 *= sch;
    l4.x = l4.x * sc.x + ps.x;
    l4.y = l4.y * sc.y + ps.y;
    l4.z = l4.z * sc.z + ps.z;
    l4.w = l4.w * sc.w + ps.w;
    m4 = mn;
    // phase B: pure accumulate, unroll 4 to keep gathers in flight
    int k = 0;
    for (; k + 4 <= len; k += 4) {
      int s0 = sbuf[wv][k], s1 = sbuf[wv][k + 1];
      int s2 = sbuf[wv][k + 2], s3 = sbuf[wv][k + 3];
      float q0 = pbuf[wv][k * 4 + head], q1 = pbuf[wv][(k + 1) * 4 + head];
      float q2 = pbuf[wv][(k + 2) * 4 + head], q3 = pbuf[wv][(k + 3) * 4 + head];
      float2 h0 = *(const float2*)(hin + (size_t)s0 * 128 + ch);
      float2 h1 = *(const float2*)(hin + (size_t)s1 * 128 + ch);
      float2 h2 = *(const float2*)(hin + (size_t)s2 * 128 + ch);
      float2 h3 = *(const float2*)(hin + (size_t)s3 * 128 + ch);
      acc0 += q0 * h0.x; acc1 += q0 * h0.y;
      acc0 += q1 * h1.x; acc1 += q1 * h1.y;
      acc0 += q2 * h2.x; acc1 += q2 * h2.y;
      acc0 += q3 * h3.x; acc1 += q3 * h3.y;
    }
    for (; k < len; ++k) {
      int s = sbuf[wv][k];
      float q = pbuf[wv][k * 4 + head];
      float2 hv = *(const float2*)(hin + (size_t)s * 128 + ch);
      acc0 += q * hv.x; acc1 += q * hv.y;
    }
  }

  // self loop: edge feature contribution = mean of incoming raw alpha_e
#pragma unroll
  for (int off = 32; off; off >>= 1) {
    sa.x += __shfl_xor(sa.x, off);
    sa.y += __shfl_xor(sa.y, off);
    sa.z += __shfl_xor(sa.z, off);
    sa.w += __shfl_xor(sa.w, off);
  }
  const int deg = j1 - j0;
  const float invd = 1.f / fmaxf((float)deg, 1.f);
  const float4 sn = *(const float4*)(ssc + (size_t)node * 4);
  float4 al;
  al.x = leaky02(sn.x + dv.x + sa.x * invd);
  al.y = leaky02(sn.y + dv.y + sa.y * invd);
  al.z = leaky02(sn.z + dv.z + sa.z * invd);
  al.w = leaky02(sn.w + dv.w + sa.w * invd);
  float4 mn = make_float4(fmaxf(m4.x, al.x), fmaxf(m4.y, al.y),
                          fmaxf(m4.z, al.z), fmaxf(m4.w, al.w));
  float4 sc, p4;
  sc.x = __expf(m4.x - mn.x); p4.x = __expf(al.x - mn.x);
  sc.y = __expf(m4.y - mn.y); p4.y = __expf(al.y - mn.y);
  sc.z = __expf(m4.z - mn.z); p4.z = __expf(al.z - mn.z);
  sc.w = __expf(m4.w - mn.w); p4.w = __expf(al.w - mn.w);
  const float sch = sel4(sc, head);
  const float ph = sel4(p4, head);
  const float2 hv = *(const float2*)(hin + (size_t)node * 128 + ch);
  acc0 = acc0 * sch + ph * hv.x;
  acc1 = acc1 * sch + ph * hv.y;
  l4.x = l4.x * sc.x + p4.x;
  l4.y = l4.y * sc.y + p4.y;
  l4.z = l4.z * sc.z + p4.z;
  l4.w = l4.w * sc.w + p4.w;
  const float invl = 1.f / (sel4(l4, head) + 1e-16f);
  float o0 = acc0 * invl + bias[ch];
  float o1 = acc1 * invl + bias[ch + 1];
  hout[(size_t)node * 128 + ch] = fmaxf(o0, 0.f);
  hout[(size_t)node * 128 + ch + 1] = fmaxf(o1, 0.f);
}

// logits = h @ Wlin.T + blin; log_softmax over 40 classes. one wave per node.
__global__ __launch_bounds__(256) void classifier_kernel(const float* __restrict__ h,
                                                         const float* __restrict__ Wlin,
                                                         const float* __restrict__ blin,
                                                         float* __restrict__ out, int n) {
  __shared__ float wt[128 * 40];
  __shared__ float hs[4][128];
  for (int idx = threadIdx.x; idx < 40 * 128; idx += 256) {
    int c = idx >> 7, k = idx & 127;
    wt[k * 40 + c] = Wlin[idx];
  }
  int w = threadIdx.x >> 6, lane = threadIdx.x & 63;
  int node = blockIdx.x * 4 + w;
  if (node < n) {
    hs[w][lane] = h[(size_t)node * 128 + lane];
    hs[w][lane + 64] = h[(size_t)node * 128 + lane + 64];
  }
  __syncthreads();
  if (node >= n) return;
  float logit = -INFINITY;
  if (lane < 40) {
    float acc = blin[lane];
#pragma unroll 4
    for (int k = 0; k < 128; ++k) acc += hs[w][k] * wt[k * 40 + lane];
    logit = acc;
  }
  float mx = logit;
#pragma unroll
  for (int off = 32; off; off >>= 1) mx = fmaxf(mx, __shfl_xor(mx, off));
  float ex = (lane < 40) ? __expf(logit - mx) : 0.f;
  float sm = ex;
#pragma unroll
  for (int off = 32; off; off >>= 1) sm += __shfl_xor(sm, off);
  if (lane < 40) out[(size_t)node * 40 + lane] = logit - mx - __logf(sm);
}

extern "C" void kernel_launch(void* const* d_in, const int* in_sizes, int n_in,
                              void* d_out, int out_size, void* d_ws, size_t ws_size,
                              hipStream_t stream) {
  const float* x    = (const float*)d_in[0];
  const int*   eidx = (const int*)d_in[1];
  const float* ea   = (const float*)d_in[2];
  const float* W1   = (const float*)d_in[3];
  const float* as1  = (const float*)d_in[4];
  const float* ad1  = (const float*)d_in[5];
  const float* ae1w = (const float*)d_in[6];
  const float* We1  = (const float*)d_in[7];
  const float* b1   = (const float*)d_in[8];
  const float* W2   = (const float*)d_in[9];
  const float* as2  = (const float*)d_in[10];
  const float* ad2  = (const float*)d_in[11];
  const float* ae2w = (const float*)d_in[12];
  const float* We2  = (const float*)d_in[13];
  const float* b2   = (const float*)d_in[14];
  const float* Wlin = (const float*)d_in[15];
  const float* blin = (const float*)d_in[16];
  float* out = (float*)d_out;

  const int N = in_sizes[0] / 64;
  const int E = in_sizes[1] / 2;
  const int* src = eidx;
  const int* dst = eidx + E;

  char* wsb = (char*)d_ws;
  size_t off = 0;
  auto alloc = [&](size_t bytes) -> void* {
    void* p = wsb + off;
    off = (off + bytes + 255) & ~(size_t)255;
    return p;
  };
  int*   cnt   = (int*)alloc((size_t)N * 4);
  int*   offs  = (int*)alloc((size_t)(N + 1) * 4);
  int*   wpos  = (int*)alloc((size_t)N * 4);
  int*   bsum  = (int*)alloc(64 * 4);
  int*   elist = (int*)alloc((size_t)E * 4);
  int*   srcS  = (int*)alloc((size_t)E * 4);
  float* Wa    = (float*)alloc(128 * 4);
  float* ssc   = (float*)alloc((size_t)N * 4 * 4);
  float* dsc   = (float*)alloc((size_t)N * 4 * 4);
  unsigned short* aeEb = (unsigned short*)alloc((size_t)E * 4 * 2);
  float* hA    = (float*)alloc((size_t)N * 128 * 4);
  float* hB    = (float*)alloc((size_t)N * 128 * 4);

  const int ge = (E + 255) / 256;
  const int gg = (N + 63) / 64;
  const int gn = (N + 3) / 4;
  const int gs = (N + 1023) / 1024;  // 49 blocks for N=50000 (<=64 required)

  hipMemsetAsync(cnt, 0, (size_t)N * 4, stream);
  count_kernel<<<ge, 256, 0, stream>>>(dst, cnt, E);
  scan1_kernel<<<gs, 1024, 0, stream>>>(cnt, offs, bsum, N);
  scan2_kernel<<<1, 64, 0, stream>>>(bsum, gs);
  scan3_kernel<<<gs, 1024, 0, stream>>>(cnt, offs, bsum, wpos, N);
  fill_kernel<<<ge, 256, 0, stream>>>(src, dst, wpos, elist, srcS, E);
  wa_kernel<<<1, 128, 0, stream>>>(ae1w, We1, ae2w, We2, Wa);

  // ---- layer 1 ----
  alphae_kernel<<<ge, 256, 0, stream>>>(elist, ea, Wa, aeEb, E);
  gemm_kernel<<<gg, 256, 0, stream>>>(x, W1, hA, N, 64);
  score_kernel<<<gn, 256, 0, stream>>>(hA, as1, ad1, ssc, dsc, N);
  agg_kernel<<<gn, 256, 0, stream>>>(hA, ssc, dsc, aeEb, offs, srcS, b1, hB, N);

  // ---- layer 2 ----
  alphae_kernel<<<ge, 256, 0, stream>>>(elist, ea, Wa + 64, aeEb, E);
  gemm_kernel<<<gg, 256, 0, stream>>>(hB, W2, hA, N, 128);
  score_kernel<<<gn, 256, 0, stream>>>(hA, as2, ad2, ssc, dsc, N);
  agg_kernel<<<gn, 256, 0, stream>>>(hA, ssc, dsc, aeEb, offs, srcS, b2, hB, N);

  // ---- classifier + log_softmax ----
  classifier_kernel<<<gn, 256, 0, stream>>>(hB, Wlin, blin, out, N);
}

// Round 4
// 700.058 us; speedup vs baseline: 1.7103x; 1.2114x over previous
//
#include <hip/hip_runtime.h>
#include <hip/hip_bf16.h>
#include <math.h>

// ---------------------------------------------------------------------------
// GAT 2-layer + classifier.
// R3: bf16 h everywhere (fp32 math in-kernel), MFMA bf16 GEMMs, single int2
//     scatter in fill, one alphae pass computing both layers' alpha_e.
// ---------------------------------------------------------------------------

typedef __attribute__((ext_vector_type(8))) short short8;
typedef __attribute__((ext_vector_type(4))) float floatx4;

__device__ __forceinline__ unsigned short f2bf(float f) {
  unsigned u = __float_as_uint(f);
  unsigned r = u + 0x7FFFu + ((u >> 16) & 1u);
  return (unsigned short)(r >> 16);
}
__device__ __forceinline__ float bf2f(unsigned short b) {
  return __uint_as_float(((unsigned)b) << 16);
}

__global__ __launch_bounds__(256) void count_kernel(const int* __restrict__ dst,
                                                    int* __restrict__ cnt, int E) {
  int e = blockIdx.x * 256 + threadIdx.x;
  if (e < E) atomicAdd(&cnt[dst[e]], 1);
}

__global__ __launch_bounds__(1024) void scan1_kernel(const int* __restrict__ cnt,
                                                     int* __restrict__ offs,
                                                     int* __restrict__ bsum, int n) {
  __shared__ int buf[1024];
  int i = blockIdx.x * 1024 + threadIdx.x;
  int v = (i < n) ? cnt[i] : 0;
  buf[threadIdx.x] = v;
  __syncthreads();
  for (int off = 1; off < 1024; off <<= 1) {
    int t = (threadIdx.x >= (unsigned)off) ? buf[threadIdx.x - off] : 0;
    __syncthreads();
    buf[threadIdx.x] += t;
    __syncthreads();
  }
  if (i < n) offs[i + 1] = buf[threadIdx.x];
  if (threadIdx.x == 1023) bsum[blockIdx.x] = buf[1023];
}

__global__ __launch_bounds__(64) void scan2_kernel(int* __restrict__ bsum, int nb) {
  int lane = threadIdx.x;
  int v = (lane < nb) ? bsum[lane] : 0;
#pragma unroll
  for (int off = 1; off < 64; off <<= 1) {
    int t = __shfl_up(v, off);
    if (lane >= off) v += t;
  }
  if (lane < nb) bsum[lane] = v;
}

__global__ __launch_bounds__(1024) void scan3_kernel(const int* __restrict__ cnt,
                                                     int* __restrict__ offs,
                                                     const int* __restrict__ bsum,
                                                     int* __restrict__ wpos, int n) {
  int i = blockIdx.x * 1024 + threadIdx.x;
  if (i >= n) return;
  int add = (blockIdx.x > 0) ? bsum[blockIdx.x - 1] : 0;
  int incl = offs[i + 1] + add;
  offs[i + 1] = incl;
  wpos[i] = incl - cnt[i];
  if (i == 0) offs[0] = 0;
}

// single 8B scattered store per edge: {src, e}
__global__ __launch_bounds__(256) void fill_kernel(const int* __restrict__ src,
                                                   const int* __restrict__ dst,
                                                   int* __restrict__ wpos,
                                                   int2* __restrict__ epair, int E) {
  int e = blockIdx.x * 256 + threadIdx.x;
  if (e < E) {
    int p = atomicAdd(&wpos[dst[e]], 1);
    int2 pr; pr.x = src[e]; pr.y = e;
    epair[p] = pr;
  }
}

// Wa[layer][h][d] = sum_c ae[h][c] * We[h*32+c][d]   (two layers, 128 threads)
__global__ __launch_bounds__(128) void wa_kernel(const float* __restrict__ ae1,
                                                 const float* __restrict__ We1,
                                                 const float* __restrict__ ae2,
                                                 const float* __restrict__ We2,
                                                 float* __restrict__ Wa) {
  int t = threadIdx.x;
  const float* ae = (t < 64) ? ae1 : ae2;
  const float* We = (t < 64) ? We1 : We2;
  int h = (t >> 4) & 3;
  int d = t & 15;
  float s = 0.f;
  for (int c = 0; c < 32; ++c) s += ae[h * 32 + c] * We[(h * 32 + c) * 16 + d];
  Wa[t] = s;
}

// fp32 -> bf16 convert
__global__ __launch_bounds__(256) void cvt_kernel(const float* __restrict__ in,
                                                  unsigned short* __restrict__ out, int n) {
  int i = blockIdx.x * 256 + threadIdx.x;
  if (i < n) out[i] = f2bf(in[i]);
}

// per CSR slot j: e=epair[j].y; alpha_e for BOTH layers (8 heads) -> ae12 bf16x8;
// also emit srcS[j] (4B stream for agg).
__global__ __launch_bounds__(256) void alphae12_kernel(const int2* __restrict__ epair,
                                                       const float* __restrict__ ea,
                                                       const float* __restrict__ Wa,
                                                       unsigned short* __restrict__ ae12,
                                                       int* __restrict__ srcS, int E) {
  __shared__ float wa[128];
  if (threadIdx.x < 128) wa[threadIdx.x] = Wa[threadIdx.x];
  __syncthreads();
  int j = blockIdx.x * 256 + threadIdx.x;
  if (j >= E) return;
  const int2 pr = epair[j];
  const int e = pr.y;
  srcS[j] = pr.x;
  const float4* p = (const float4*)(ea + (size_t)e * 16);
  float4 q0 = p[0], q1 = p[1], q2 = p[2], q3 = p[3];
  float v[16] = {q0.x, q0.y, q0.z, q0.w, q1.x, q1.y, q1.z, q1.w,
                 q2.x, q2.y, q2.z, q2.w, q3.x, q3.y, q3.z, q3.w};
  unsigned short rr[8];
#pragma unroll
  for (int h = 0; h < 8; ++h) {
    float s = 0.f;
#pragma unroll
    for (int d = 0; d < 16; ++d) s += v[d] * wa[h * 16 + d];
    rr[h] = f2bf(s);
  }
  ushort4 lo; lo.x = rr[0]; lo.y = rr[1]; lo.z = rr[2]; lo.w = rr[3];
  ushort4 hi; hi.x = rr[4]; hi.y = rr[5]; hi.z = rr[6]; hi.w = rr[7];
  *(ushort4*)(ae12 + (size_t)j * 8) = lo;
  *(ushort4*)(ae12 + (size_t)j * 8 + 4) = hi;
}

// bf16 MFMA GEMM: H[n][o] = sum_k X[n][k]*W[o][k]. Block: 64 nodes x 128 outs,
// 4 waves, each wave 64x32 (4 m-tiles x 2 n-tiles of 16x16x32 MFMA).
__global__ __launch_bounds__(256) void gemm_mfma_kernel(const unsigned short* __restrict__ X,
                                                        const unsigned short* __restrict__ Wb,
                                                        unsigned short* __restrict__ H,
                                                        int n, int K) {
  const int w = threadIdx.x >> 6;
  const int lane = threadIdx.x & 63;
  const int m0 = blockIdx.x * 64;
  const int quad = lane >> 4;
  const int l15 = lane & 15;
  floatx4 acc[4][2];
#pragma unroll
  for (int mt = 0; mt < 4; ++mt)
#pragma unroll
    for (int nt = 0; nt < 2; ++nt) acc[mt][nt] = (floatx4)(0.f);

  int rowm[4];
#pragma unroll
  for (int mt = 0; mt < 4; ++mt) {
    int r = m0 + mt * 16 + l15;
    rowm[mt] = (r < n) ? r : (n - 1);
  }
  const int ncol0 = (w << 5) + l15;

  for (int kc = 0; kc < K; kc += 32) {
    const int koff = kc + (quad << 3);
    short8 a[4], b[2];
#pragma unroll
    for (int mt = 0; mt < 4; ++mt)
      a[mt] = *(const short8*)(X + (size_t)rowm[mt] * K + koff);
#pragma unroll
    for (int nt = 0; nt < 2; ++nt)
      b[nt] = *(const short8*)(Wb + (size_t)(ncol0 + nt * 16) * K + koff);
#pragma unroll
    for (int mt = 0; mt < 4; ++mt)
#pragma unroll
      for (int nt = 0; nt < 2; ++nt)
        acc[mt][nt] = __builtin_amdgcn_mfma_f32_16x16x32_bf16(a[mt], b[nt], acc[mt][nt], 0, 0, 0);
  }
#pragma unroll
  for (int mt = 0; mt < 4; ++mt) {
    const int rbase = m0 + mt * 16 + (quad << 2);
#pragma unroll
    for (int nt = 0; nt < 2; ++nt) {
      const int col = ncol0 + nt * 16;
#pragma unroll
      for (int r = 0; r < 4; ++r) {
        const int row = rbase + r;
        if (row < n) H[(size_t)row * 128 + col] = f2bf(acc[mt][nt][r]);
      }
    }
  }
}

// per-node head scores from bf16 h
__global__ __launch_bounds__(256) void score_kernel(const unsigned short* __restrict__ h,
                                                    const float* __restrict__ a_s,
                                                    const float* __restrict__ a_d,
                                                    float* __restrict__ ssc,
                                                    float* __restrict__ dsc, int n) {
  int gid = blockIdx.x * 256 + threadIdx.x;
  int node = gid >> 6;
  int lane = threadIdx.x & 63;
  if (node >= n) return;
  int ch = lane * 2;
  ushort2 hq = *(const ushort2*)(h + (size_t)node * 128 + ch);
  float h0 = bf2f(hq.x), h1 = bf2f(hq.y);
  float ps = h0 * a_s[ch] + h1 * a_s[ch + 1];
  float pd = h0 * a_d[ch] + h1 * a_d[ch + 1];
#pragma unroll
  for (int off = 8; off; off >>= 1) {
    ps += __shfl_xor(ps, off, 16);
    pd += __shfl_xor(pd, off, 16);
  }
  if ((lane & 15) == 0) {
    int head = lane >> 4;
    ssc[node * 4 + head] = ps;
    dsc[node * 4 + head] = pd;
  }
}

__device__ __forceinline__ float leaky02(float a) { return a > 0.f ? a : 0.2f * a; }
__device__ __forceinline__ float sel4(float4 v, int h) {
  return (h == 0) ? v.x : (h == 1) ? v.y : (h == 2) ? v.z : v.w;
}

// one wave per node, chunked two-phase online-softmax aggregation (bf16 h).
// laeoff selects layer-1 (0) or layer-2 (4) alpha half in ae12 (stride 8).
__global__ __launch_bounds__(256) void agg_kernel(const unsigned short* __restrict__ hin,
                                                  const float* __restrict__ ssc,
                                                  const float* __restrict__ dsc,
                                                  const unsigned short* __restrict__ ae12,
                                                  int laeoff,
                                                  const int* __restrict__ offs,
                                                  const int* __restrict__ srcS,
                                                  const float* __restrict__ bias,
                                                  unsigned short* __restrict__ hout, int n) {
  __shared__ int sbuf[4][64];
  __shared__ float pbuf[4][64 * 4];
  const int wv = threadIdx.x >> 6;
  const int lane = threadIdx.x & 63;
  const int node = blockIdx.x * 4 + wv;
  if (node >= n) return;
  const int head = lane >> 4;
  const int ch = lane * 2;
  const float4 dv = *(const float4*)(dsc + (size_t)node * 4);
  float4 m4 = make_float4(-INFINITY, -INFINITY, -INFINITY, -INFINITY);
  float4 l4 = make_float4(0.f, 0.f, 0.f, 0.f);
  float4 sa = make_float4(0.f, 0.f, 0.f, 0.f);
  float acc0 = 0.f, acc1 = 0.f;
  const int j0 = offs[node], j1 = offs[node + 1];

  for (int jc = j0; jc < j1; jc += 64) {
    const int len = min(64, j1 - jc);
    float4 a4 = make_float4(-INFINITY, -INFINITY, -INFINITY, -INFINITY);
    int sv = 0;
    if (lane < len) {
      const int j = jc + lane;
      sv = srcS[j];
      const ushort4 aq = *(const ushort4*)(ae12 + (size_t)j * 8 + laeoff);
      const float4 ae4 = make_float4(bf2f(aq.x), bf2f(aq.y), bf2f(aq.z), bf2f(aq.w));
      const float4 ss4 = *(const float4*)(ssc + (size_t)sv * 4);
      sa.x += ae4.x; sa.y += ae4.y; sa.z += ae4.z; sa.w += ae4.w;
      a4.x = leaky02(ss4.x + dv.x + ae4.x);
      a4.y = leaky02(ss4.y + dv.y + ae4.y);
      a4.z = leaky02(ss4.z + dv.z + ae4.z);
      a4.w = leaky02(ss4.w + dv.w + ae4.w);
    }
    sbuf[wv][lane] = sv;
    float4 cm = a4;
#pragma unroll
    for (int off = 32; off; off >>= 1) {
      cm.x = fmaxf(cm.x, __shfl_xor(cm.x, off));
      cm.y = fmaxf(cm.y, __shfl_xor(cm.y, off));
      cm.z = fmaxf(cm.z, __shfl_xor(cm.z, off));
      cm.w = fmaxf(cm.w, __shfl_xor(cm.w, off));
    }
    float4 mn = make_float4(fmaxf(m4.x, cm.x), fmaxf(m4.y, cm.y),
                            fmaxf(m4.z, cm.z), fmaxf(m4.w, cm.w));
    float4 p4;
    p4.x = (lane < len) ? __expf(a4.x - mn.x) : 0.f;
    p4.y = (lane < len) ? __expf(a4.y - mn.y) : 0.f;
    p4.z = (lane < len) ? __expf(a4.z - mn.z) : 0.f;
    p4.w = (lane < len) ? __expf(a4.w - mn.w) : 0.f;
    *(float4*)(&pbuf[wv][lane * 4]) = p4;
    float4 ps = p4;
#pragma unroll
    for (int off = 32; off; off >>= 1) {
      ps.x += __shfl_xor(ps.x, off);
      ps.y += __shfl_xor(ps.y, off);
      ps.z += __shfl_xor(ps.z, off);
      ps.w += __shfl_xor(ps.w, off);
    }
    float4 sc;
    sc.x = __expf(m4.x - mn.x);
    sc.y = __expf(m4.y - mn.y);
    sc.z = __expf(m4.z - mn.z);
    sc.w = __expf(m4.w - mn.w);
    const float sch = sel4(sc, head);
    acc0 *= sch; acc1 *= sch;
    l4.x = l4.x * sc.x + ps.x;
    l4.y = l4.y * sc.y + ps.y;
    l4.z = l4.z * sc.z + ps.z;
    l4.w = l4.w * sc.w + ps.w;
    m4 = mn;
    int k = 0;
    for (; k + 4 <= len; k += 4) {
      int s0 = sbuf[wv][k], s1 = sbuf[wv][k + 1];
      int s2 = sbuf[wv][k + 2], s3 = sbuf[wv][k + 3];
      float q0 = pbuf[wv][k * 4 + head], q1 = pbuf[wv][(k + 1) * 4 + head];
      float q2 = pbuf[wv][(k + 2) * 4 + head], q3 = pbuf[wv][(k + 3) * 4 + head];
      ushort2 u0 = *(const ushort2*)(hin + (size_t)s0 * 128 + ch);
      ushort2 u1 = *(const ushort2*)(hin + (size_t)s1 * 128 + ch);
      ushort2 u2 = *(const ushort2*)(hin + (size_t)s2 * 128 + ch);
      ushort2 u3 = *(const ushort2*)(hin + (size_t)s3 * 128 + ch);
      acc0 += q0 * bf2f(u0.x); acc1 += q0 * bf2f(u0.y);
      acc0 += q1 * bf2f(u1.x); acc1 += q1 * bf2f(u1.y);
      acc0 += q2 * bf2f(u2.x); acc1 += q2 * bf2f(u2.y);
      acc0 += q3 * bf2f(u3.x); acc1 += q3 * bf2f(u3.y);
    }
    for (; k < len; ++k) {
      int s = sbuf[wv][k];
      float q = pbuf[wv][k * 4 + head];
      ushort2 u = *(const ushort2*)(hin + (size_t)s * 128 + ch);
      acc0 += q * bf2f(u.x); acc1 += q * bf2f(u.y);
    }
  }

#pragma unroll
  for (int off = 32; off; off >>= 1) {
    sa.x += __shfl_xor(sa.x, off);
    sa.y += __shfl_xor(sa.y, off);
    sa.z += __shfl_xor(sa.z, off);
    sa.w += __shfl_xor(sa.w, off);
  }
  const int deg = j1 - j0;
  const float invd = 1.f / fmaxf((float)deg, 1.f);
  const float4 sn = *(const float4*)(ssc + (size_t)node * 4);
  float4 al;
  al.x = leaky02(sn.x + dv.x + sa.x * invd);
  al.y = leaky02(sn.y + dv.y + sa.y * invd);
  al.z = leaky02(sn.z + dv.z + sa.z * invd);
  al.w = leaky02(sn.w + dv.w + sa.w * invd);
  float4 mn = make_float4(fmaxf(m4.x, al.x), fmaxf(m4.y, al.y),
                          fmaxf(m4.z, al.z), fmaxf(m4.w, al.w));
  float4 sc, p4;
  sc.x = __expf(m4.x - mn.x); p4.x = __expf(al.x - mn.x);
  sc.y = __expf(m4.y - mn.y); p4.y = __expf(al.y - mn.y);
  sc.z = __expf(m4.z - mn.z); p4.z = __expf(al.z - mn.z);
  sc.w = __expf(m4.w - mn.w); p4.w = __expf(al.w - mn.w);
  const float sch = sel4(sc, head);
  const float ph = sel4(p4, head);
  ushort2 uh = *(const ushort2*)(hin + (size_t)node * 128 + ch);
  acc0 = acc0 * sch + ph * bf2f(uh.x);
  acc1 = acc1 * sch + ph * bf2f(uh.y);
  l4.x = l4.x * sc.x + p4.x;
  l4.y = l4.y * sc.y + p4.y;
  l4.z = l4.z * sc.z + p4.z;
  l4.w = l4.w * sc.w + p4.w;
  const float invl = 1.f / (sel4(l4, head) + 1e-16f);
  float o0 = acc0 * invl + bias[ch];
  float o1 = acc1 * invl + bias[ch + 1];
  ushort2 o; o.x = f2bf(fmaxf(o0, 0.f)); o.y = f2bf(fmaxf(o1, 0.f));
  *(ushort2*)(hout + (size_t)node * 128 + ch) = o;
}

// logits = h @ Wlin.T + blin; log_softmax over 40 classes. one wave per node.
__global__ __launch_bounds__(256) void classifier_kernel(const unsigned short* __restrict__ h,
                                                         const float* __restrict__ Wlin,
                                                         const float* __restrict__ blin,
                                                         float* __restrict__ out, int n) {
  __shared__ float wt[128 * 40];
  __shared__ float hs[4][128];
  for (int idx = threadIdx.x; idx < 40 * 128; idx += 256) {
    int c = idx >> 7, k = idx & 127;
    wt[k * 40 + c] = Wlin[idx];
  }
  int w = threadIdx.x >> 6, lane = threadIdx.x & 63;
  int node = blockIdx.x * 4 + w;
  if (node < n) {
    hs[w][lane] = bf2f(h[(size_t)node * 128 + lane]);
    hs[w][lane + 64] = bf2f(h[(size_t)node * 128 + lane + 64]);
  }
  __syncthreads();
  if (node >= n) return;
  float logit = -INFINITY;
  if (lane < 40) {
    float acc = blin[lane];
#pragma unroll 4
    for (int k = 0; k < 128; ++k) acc += hs[w][k] * wt[k * 40 + lane];
    logit = acc;
  }
  float mx = logit;
#pragma unroll
  for (int off = 32; off; off >>= 1) mx = fmaxf(mx, __shfl_xor(mx, off));
  float ex = (lane < 40) ? __expf(logit - mx) : 0.f;
  float sm = ex;
#pragma unroll
  for (int off = 32; off; off >>= 1) sm += __shfl_xor(sm, off);
  if (lane < 40) out[(size_t)node * 40 + lane] = logit - mx - __logf(sm);
}

extern "C" void kernel_launch(void* const* d_in, const int* in_sizes, int n_in,
                              void* d_out, int out_size, void* d_ws, size_t ws_size,
                              hipStream_t stream) {
  const float* x    = (const float*)d_in[0];
  const int*   eidx = (const int*)d_in[1];
  const float* ea   = (const float*)d_in[2];
  const float* W1   = (const float*)d_in[3];
  const float* as1  = (const float*)d_in[4];
  const float* ad1  = (const float*)d_in[5];
  const float* ae1w = (const float*)d_in[6];
  const float* We1  = (const float*)d_in[7];
  const float* b1   = (const float*)d_in[8];
  const float* W2   = (const float*)d_in[9];
  const float* as2  = (const float*)d_in[10];
  const float* ad2  = (const float*)d_in[11];
  const float* ae2w = (const float*)d_in[12];
  const float* We2  = (const float*)d_in[13];
  const float* b2   = (const float*)d_in[14];
  const float* Wlin = (const float*)d_in[15];
  const float* blin = (const float*)d_in[16];
  float* out = (float*)d_out;

  const int N = in_sizes[0] / 64;
  const int E = in_sizes[1] / 2;
  const int* src = eidx;
  const int* dst = eidx + E;

  char* wsb = (char*)d_ws;
  size_t off = 0;
  auto alloc = [&](size_t bytes) -> void* {
    void* p = wsb + off;
    off = (off + bytes + 255) & ~(size_t)255;
    return p;
  };
  int*   cnt   = (int*)alloc((size_t)N * 4);
  int*   offs  = (int*)alloc((size_t)(N + 1) * 4);
  int*   wpos  = (int*)alloc((size_t)N * 4);
  int*   bsum  = (int*)alloc(64 * 4);
  int2*  epair = (int2*)alloc((size_t)E * 8);
  int*   srcS  = (int*)alloc((size_t)E * 4);
  float* Wa    = (float*)alloc(128 * 4);
  unsigned short* xb  = (unsigned short*)alloc((size_t)N * 64 * 2);
  unsigned short* Wb1 = (unsigned short*)alloc(128 * 64 * 2);
  unsigned short* Wb2 = (unsigned short*)alloc(128 * 128 * 2);
  float* ssc   = (float*)alloc((size_t)N * 4 * 4);
  float* dsc   = (float*)alloc((size_t)N * 4 * 4);
  unsigned short* ae12 = (unsigned short*)alloc((size_t)E * 8 * 2);
  unsigned short* hA   = (unsigned short*)alloc((size_t)N * 128 * 2);
  unsigned short* hB   = (unsigned short*)alloc((size_t)N * 128 * 2);

  const int ge = (E + 255) / 256;
  const int gg = (N + 63) / 64;
  const int gn = (N + 3) / 4;
  const int gs = (N + 1023) / 1024;

  hipMemsetAsync(cnt, 0, (size_t)N * 4, stream);
  count_kernel<<<ge, 256, 0, stream>>>(dst, cnt, E);
  scan1_kernel<<<gs, 1024, 0, stream>>>(cnt, offs, bsum, N);
  scan2_kernel<<<1, 64, 0, stream>>>(bsum, gs);
  scan3_kernel<<<gs, 1024, 0, stream>>>(cnt, offs, bsum, wpos, N);
  fill_kernel<<<ge, 256, 0, stream>>>(src, dst, wpos, epair, E);
  wa_kernel<<<1, 128, 0, stream>>>(ae1w, We1, ae2w, We2, Wa);
  cvt_kernel<<<(N * 64 + 255) / 256, 256, 0, stream>>>(x, xb, N * 64);
  cvt_kernel<<<(128 * 64 + 255) / 256, 256, 0, stream>>>(W1, Wb1, 128 * 64);
  cvt_kernel<<<(128 * 128 + 255) / 256, 256, 0, stream>>>(W2, Wb2, 128 * 128);
  alphae12_kernel<<<ge, 256, 0, stream>>>(epair, ea, Wa, ae12, srcS, E);

  // ---- layer 1 ----
  gemm_mfma_kernel<<<gg, 256, 0, stream>>>(xb, Wb1, hA, N, 64);
  score_kernel<<<gn, 256, 0, stream>>>(hA, as1, ad1, ssc, dsc, N);
  agg_kernel<<<gn, 256, 0, stream>>>(hA, ssc, dsc, ae12, 0, offs, srcS, b1, hB, N);

  // ---- layer 2 ----
  gemm_mfma_kernel<<<gg, 256, 0, stream>>>(hB, Wb2, hA, N, 128);
  score_kernel<<<gn, 256, 0, stream>>>(hA, as2, ad2, ssc, dsc, N);
  agg_kernel<<<gn, 256, 0, stream>>>(hA, ssc, dsc, ae12, 4, offs, srcS, b2, hB, N);

  // ---- classifier + log_softmax ----
  classifier_kernel<<<gn, 256, 0, stream>>>(hB, Wlin, blin, out, N);
}

// Round 5
// 568.397 us; speedup vs baseline: 2.1065x; 1.2316x over previous
//
#include <hip/hip_runtime.h>
#include <hip/hip_bf16.h>
#include <math.h>

// ---------------------------------------------------------------------------
// GAT 2-layer + classifier.
// R4: CSR build via two-level bucket sort (LDS-staged, XCD-local writes)
//     replacing atomic-scatter fill (101 MB line-bounce -> ~40 MB).
//     bf16 h + MFMA GEMMs from R3 retained. binned aliases hA (ws ~72 MB).
// ---------------------------------------------------------------------------

#define CHUNK 8192
#define CAPC 12288  // max edges per 128-dst bucket (mean 4096, sigma 64)

typedef __attribute__((ext_vector_type(8))) short short8;
typedef __attribute__((ext_vector_type(4))) float floatx4;

__device__ __forceinline__ unsigned short f2bf(float f) {
  unsigned u = __float_as_uint(f);
  unsigned r = u + 0x7FFFu + ((u >> 16) & 1u);
  return (unsigned short)(r >> 16);
}
__device__ __forceinline__ float bf2f(unsigned short b) {
  return __uint_as_float(((unsigned)b) << 16);
}

// per-chunk LDS histogram over dst>>7 buckets
__global__ __launch_bounds__(512) void hist_kernel(const int* __restrict__ dst,
                                                   int* __restrict__ bucketCnt,
                                                   int E, int NB) {
  __shared__ int hist[512];
  const int tid = threadIdx.x;
  hist[tid] = 0;
  __syncthreads();
  const int e0 = blockIdx.x * CHUNK, e1 = min(e0 + CHUNK, E);
  for (int e = e0 + tid; e < e1; e += 512) atomicAdd(&hist[dst[e] >> 7], 1);
  __syncthreads();
  if (tid < NB && hist[tid]) atomicAdd(&bucketCnt[tid], hist[tid]);
}

__global__ __launch_bounds__(512) void scanB_kernel(const int* __restrict__ bucketCnt,
                                                    int* __restrict__ bucketOffs,
                                                    int* __restrict__ bucketPos,
                                                    int* __restrict__ offs,
                                                    int NB, int N, int E) {
  __shared__ int sc[512];
  const int tid = threadIdx.x;
  const int v = (tid < NB) ? bucketCnt[tid] : 0;
  sc[tid] = v;
  __syncthreads();
  for (int off = 1; off < 512; off <<= 1) {
    int t = (tid >= off) ? sc[tid - off] : 0;
    __syncthreads();
    sc[tid] += t;
    __syncthreads();
  }
  const int excl = sc[tid] - v;
  if (tid < NB) { bucketOffs[tid] = excl; bucketPos[tid] = excl; }
  if (tid == 0) { bucketOffs[NB] = E; offs[N] = E; }
}

// chunk -> bucket-grouped binned[{src, (dst&127)<<25 | e}] with run-grouped writes
__global__ __launch_bounds__(512) void partB_kernel(const int* __restrict__ src,
                                                    const int* __restrict__ dst,
                                                    int* __restrict__ bucketPos,
                                                    int2* __restrict__ binned,
                                                    int E, int NB) {
  __shared__ int hist[512], sc[512], lbase[513], gbase[512], lcnt[512];
  __shared__ int2 stage[CHUNK];
  const int tid = threadIdx.x;
  const int e0 = blockIdx.x * CHUNK;
  const int e1 = min(e0 + CHUNK, E);
  hist[tid] = 0; lcnt[tid] = 0;
  __syncthreads();
  for (int e = e0 + tid; e < e1; e += 512) atomicAdd(&hist[dst[e] >> 7], 1);
  __syncthreads();
  sc[tid] = hist[tid];
  __syncthreads();
  for (int off = 1; off < 512; off <<= 1) {
    int t = (tid >= off) ? sc[tid - off] : 0;
    __syncthreads();
    sc[tid] += t;
    __syncthreads();
  }
  lbase[tid + 1] = sc[tid];
  if (tid == 0) lbase[0] = 0;
  if (tid < NB && hist[tid] > 0) gbase[tid] = atomicAdd(&bucketPos[tid], hist[tid]);
  __syncthreads();
  for (int e = e0 + tid; e < e1; e += 512) {
    const int d = dst[e];
    const int b = d >> 7;
    const int lr = atomicAdd(&lcnt[b], 1);
    int2 v;
    v.x = src[e];
    v.y = (int)(((unsigned)(d & 127) << 25) | (unsigned)e);
    stage[lbase[b] + lr] = v;
  }
  __syncthreads();
  const int total = e1 - e0;
  for (int t = tid; t < total; t += 512) {
    int lo = 0, hi = 511;
    while (lo < hi) {
      int mid = (lo + hi + 1) >> 1;
      if (lbase[mid] <= t) lo = mid; else hi = mid - 1;
    }
    binned[gbase[lo] + (t - lbase[lo])] = stage[t];
  }
}

// per bucket: counting-sort 128 dst values, emit offs/srcS/elist (window-local)
__global__ __launch_bounds__(256) void passC_kernel(const int2* __restrict__ binned,
                                                    const int* __restrict__ bucketOffs,
                                                    int* __restrict__ srcS,
                                                    int* __restrict__ elist,
                                                    int* __restrict__ offs, int N) {
  __shared__ int cnt[128], dbase[129], dpos[128];
  __shared__ int2 stage[CAPC];
  const int tid = threadIdx.x;
  const int b = blockIdx.x;
  const int bo = bucketOffs[b], be = bucketOffs[b + 1];
  const int m = be - bo;
  if (tid < 128) { cnt[tid] = 0; dpos[tid] = 0; }
  __syncthreads();
  for (int t = tid; t < m; t += 256) {
    int2 v = binned[bo + t];
    if (t < CAPC) stage[t] = v;
    atomicAdd(&cnt[((unsigned)v.y) >> 25], 1);
  }
  __syncthreads();
  for (int off = 1; off < 128; off <<= 1) {
    int t = (tid < 128 && tid >= (unsigned)off) ? cnt[tid - off] : 0;
    __syncthreads();
    if (tid < 128) cnt[tid] += t;
    __syncthreads();
  }
  if (tid == 0) dbase[0] = 0;
  if (tid < 128) dbase[tid + 1] = cnt[tid];
  __syncthreads();
  const int dcnt = min(128, N - (b << 7));
  if (tid < dcnt) offs[(b << 7) + tid] = bo + dbase[tid];
  for (int t = tid; t < m; t += 256) {
    int2 v = (t < CAPC) ? stage[t] : binned[bo + t];
    const unsigned py = (unsigned)v.y;
    const int dl = py >> 25;
    const int p = dbase[dl] + atomicAdd(&dpos[dl], 1);
    srcS[bo + p] = v.x;
    elist[bo + p] = (int)(py & 0x1FFFFFFu);
  }
}

// Wa[layer][h][d] = sum_c ae[h][c] * We[h*32+c][d]   (two layers, 128 threads)
__global__ __launch_bounds__(128) void wa_kernel(const float* __restrict__ ae1,
                                                 const float* __restrict__ We1,
                                                 const float* __restrict__ ae2,
                                                 const float* __restrict__ We2,
                                                 float* __restrict__ Wa) {
  int t = threadIdx.x;
  const float* ae = (t < 64) ? ae1 : ae2;
  const float* We = (t < 64) ? We1 : We2;
  int h = (t >> 4) & 3;
  int d = t & 15;
  float s = 0.f;
  for (int c = 0; c < 32; ++c) s += ae[h * 32 + c] * We[(h * 32 + c) * 16 + d];
  Wa[t] = s;
}

__global__ __launch_bounds__(256) void cvt_kernel(const float* __restrict__ in,
                                                  unsigned short* __restrict__ out, int n) {
  int i = blockIdx.x * 256 + threadIdx.x;
  if (i < n) out[i] = f2bf(in[i]);
}

// per CSR slot j: e=elist[j]; alpha_e for BOTH layers (8 heads) -> ae12 bf16x8
__global__ __launch_bounds__(256) void alphae12_kernel(const int* __restrict__ elist,
                                                       const float* __restrict__ ea,
                                                       const float* __restrict__ Wa,
                                                       unsigned short* __restrict__ ae12,
                                                       int E) {
  __shared__ float wa[128];
  if (threadIdx.x < 128) wa[threadIdx.x] = Wa[threadIdx.x];
  __syncthreads();
  int j = blockIdx.x * 256 + threadIdx.x;
  if (j >= E) return;
  const int e = elist[j];
  const float4* p = (const float4*)(ea + (size_t)e * 16);
  float4 q0 = p[0], q1 = p[1], q2 = p[2], q3 = p[3];
  float v[16] = {q0.x, q0.y, q0.z, q0.w, q1.x, q1.y, q1.z, q1.w,
                 q2.x, q2.y, q2.z, q2.w, q3.x, q3.y, q3.z, q3.w};
  unsigned short rr[8];
#pragma unroll
  for (int h = 0; h < 8; ++h) {
    float s = 0.f;
#pragma unroll
    for (int d = 0; d < 16; ++d) s += v[d] * wa[h * 16 + d];
    rr[h] = f2bf(s);
  }
  ushort4 lo; lo.x = rr[0]; lo.y = rr[1]; lo.z = rr[2]; lo.w = rr[3];
  ushort4 hi; hi.x = rr[4]; hi.y = rr[5]; hi.z = rr[6]; hi.w = rr[7];
  *(ushort4*)(ae12 + (size_t)j * 8) = lo;
  *(ushort4*)(ae12 + (size_t)j * 8 + 4) = hi;
}

// bf16 MFMA GEMM: H[n][o] = sum_k X[n][k]*W[o][k]. 64 nodes x 128 outs/block.
__global__ __launch_bounds__(256) void gemm_mfma_kernel(const unsigned short* __restrict__ X,
                                                        const unsigned short* __restrict__ Wb,
                                                        unsigned short* __restrict__ H,
                                                        int n, int K) {
  const int w = threadIdx.x >> 6;
  const int lane = threadIdx.x & 63;
  const int m0 = blockIdx.x * 64;
  const int quad = lane >> 4;
  const int l15 = lane & 15;
  floatx4 acc[4][2];
#pragma unroll
  for (int mt = 0; mt < 4; ++mt)
#pragma unroll
    for (int nt = 0; nt < 2; ++nt) acc[mt][nt] = (floatx4)(0.f);

  int rowm[4];
#pragma unroll
  for (int mt = 0; mt < 4; ++mt) {
    int r = m0 + mt * 16 + l15;
    rowm[mt] = (r < n) ? r : (n - 1);
  }
  const int ncol0 = (w << 5) + l15;

  for (int kc = 0; kc < K; kc += 32) {
    const int koff = kc + (quad << 3);
    short8 a[4], b[2];
#pragma unroll
    for (int mt = 0; mt < 4; ++mt)
      a[mt] = *(const short8*)(X + (size_t)rowm[mt] * K + koff);
#pragma unroll
    for (int nt = 0; nt < 2; ++nt)
      b[nt] = *(const short8*)(Wb + (size_t)(ncol0 + nt * 16) * K + koff);
#pragma unroll
    for (int mt = 0; mt < 4; ++mt)
#pragma unroll
      for (int nt = 0; nt < 2; ++nt)
        acc[mt][nt] = __builtin_amdgcn_mfma_f32_16x16x32_bf16(a[mt], b[nt], acc[mt][nt], 0, 0, 0);
  }
#pragma unroll
  for (int mt = 0; mt < 4; ++mt) {
    const int rbase = m0 + mt * 16 + (quad << 2);
#pragma unroll
    for (int nt = 0; nt < 2; ++nt) {
      const int col = ncol0 + nt * 16;
#pragma unroll
      for (int r = 0; r < 4; ++r) {
        const int row = rbase + r;
        if (row < n) H[(size_t)row * 128 + col] = f2bf(acc[mt][nt][r]);
      }
    }
  }
}

// per-node head scores from bf16 h
__global__ __launch_bounds__(256) void score_kernel(const unsigned short* __restrict__ h,
                                                    const float* __restrict__ a_s,
                                                    const float* __restrict__ a_d,
                                                    float* __restrict__ ssc,
                                                    float* __restrict__ dsc, int n) {
  int gid = blockIdx.x * 256 + threadIdx.x;
  int node = gid >> 6;
  int lane = threadIdx.x & 63;
  if (node >= n) return;
  int ch = lane * 2;
  ushort2 hq = *(const ushort2*)(h + (size_t)node * 128 + ch);
  float h0 = bf2f(hq.x), h1 = bf2f(hq.y);
  float ps = h0 * a_s[ch] + h1 * a_s[ch + 1];
  float pd = h0 * a_d[ch] + h1 * a_d[ch + 1];
#pragma unroll
  for (int off = 8; off; off >>= 1) {
    ps += __shfl_xor(ps, off, 16);
    pd += __shfl_xor(pd, off, 16);
  }
  if ((lane & 15) == 0) {
    int head = lane >> 4;
    ssc[node * 4 + head] = ps;
    dsc[node * 4 + head] = pd;
  }
}

__device__ __forceinline__ float leaky02(float a) { return a > 0.f ? a : 0.2f * a; }
__device__ __forceinline__ float sel4(float4 v, int h) {
  return (h == 0) ? v.x : (h == 1) ? v.y : (h == 2) ? v.z : v.w;
}

// one wave per node, chunked two-phase online-softmax aggregation (bf16 h).
__global__ __launch_bounds__(256) void agg_kernel(const unsigned short* __restrict__ hin,
                                                  const float* __restrict__ ssc,
                                                  const float* __restrict__ dsc,
                                                  const unsigned short* __restrict__ ae12,
                                                  int laeoff,
                                                  const int* __restrict__ offs,
                                                  const int* __restrict__ srcS,
                                                  const float* __restrict__ bias,
                                                  unsigned short* __restrict__ hout, int n) {
  __shared__ int sbuf[4][64];
  __shared__ float pbuf[4][64 * 4];
  const int wv = threadIdx.x >> 6;
  const int lane = threadIdx.x & 63;
  const int node = blockIdx.x * 4 + wv;
  if (node >= n) return;
  const int head = lane >> 4;
  const int ch = lane * 2;
  const float4 dv = *(const float4*)(dsc + (size_t)node * 4);
  float4 m4 = make_float4(-INFINITY, -INFINITY, -INFINITY, -INFINITY);
  float4 l4 = make_float4(0.f, 0.f, 0.f, 0.f);
  float4 sa = make_float4(0.f, 0.f, 0.f, 0.f);
  float acc0 = 0.f, acc1 = 0.f;
  const int j0 = offs[node], j1 = offs[node + 1];

  for (int jc = j0; jc < j1; jc += 64) {
    const int len = min(64, j1 - jc);
    float4 a4 = make_float4(-INFINITY, -INFINITY, -INFINITY, -INFINITY);
    int sv = 0;
    if (lane < len) {
      const int j = jc + lane;
      sv = srcS[j];
      const ushort4 aq = *(const ushort4*)(ae12 + (size_t)j * 8 + laeoff);
      const float4 ae4 = make_float4(bf2f(aq.x), bf2f(aq.y), bf2f(aq.z), bf2f(aq.w));
      const float4 ss4 = *(const float4*)(ssc + (size_t)sv * 4);
      sa.x += ae4.x; sa.y += ae4.y; sa.z += ae4.z; sa.w += ae4.w;
      a4.x = leaky02(ss4.x + dv.x + ae4.x);
      a4.y = leaky02(ss4.y + dv.y + ae4.y);
      a4.z = leaky02(ss4.z + dv.z + ae4.z);
      a4.w = leaky02(ss4.w + dv.w + ae4.w);
    }
    sbuf[wv][lane] = sv;
    float4 cm = a4;
#pragma unroll
    for (int off = 32; off; off >>= 1) {
      cm.x = fmaxf(cm.x, __shfl_xor(cm.x, off));
      cm.y = fmaxf(cm.y, __shfl_xor(cm.y, off));
      cm.z = fmaxf(cm.z, __shfl_xor(cm.z, off));
      cm.w = fmaxf(cm.w, __shfl_xor(cm.w, off));
    }
    float4 mn = make_float4(fmaxf(m4.x, cm.x), fmaxf(m4.y, cm.y),
                            fmaxf(m4.z, cm.z), fmaxf(m4.w, cm.w));
    float4 p4;
    p4.x = (lane < len) ? __expf(a4.x - mn.x) : 0.f;
    p4.y = (lane < len) ? __expf(a4.y - mn.y) : 0.f;
    p4.z = (lane < len) ? __expf(a4.z - mn.z) : 0.f;
    p4.w = (lane < len) ? __expf(a4.w - mn.w) : 0.f;
    *(float4*)(&pbuf[wv][lane * 4]) = p4;
    float4 ps = p4;
#pragma unroll
    for (int off = 32; off; off >>= 1) {
      ps.x += __shfl_xor(ps.x, off);
      ps.y += __shfl_xor(ps.y, off);
      ps.z += __shfl_xor(ps.z, off);
      ps.w += __shfl_xor(ps.w, off);
    }
    float4 sc;
    sc.x = __expf(m4.x - mn.x);
    sc.y = __expf(m4.y - mn.y);
    sc.z = __expf(m4.z - mn.z);
    sc.w = __expf(m4.w - mn.w);
    const float sch = sel4(sc, head);
    acc0 *= sch; acc1 *= sch;
    l4.x = l4.x * sc.x + ps.x;
    l4.y = l4.y * sc.y + ps.y;
    l4.z = l4.z * sc.z + ps.z;
    l4.w = l4.w * sc.w + ps.w;
    m4 = mn;
    int k = 0;
    for (; k + 4 <= len; k += 4) {
      int s0 = sbuf[wv][k], s1 = sbuf[wv][k + 1];
      int s2 = sbuf[wv][k + 2], s3 = sbuf[wv][k + 3];
      float q0 = pbuf[wv][k * 4 + head], q1 = pbuf[wv][(k + 1) * 4 + head];
      float q2 = pbuf[wv][(k + 2) * 4 + head], q3 = pbuf[wv][(k + 3) * 4 + head];
      ushort2 u0 = *(const ushort2*)(hin + (size_t)s0 * 128 + ch);
      ushort2 u1 = *(const ushort2*)(hin + (size_t)s1 * 128 + ch);
      ushort2 u2 = *(const ushort2*)(hin + (size_t)s2 * 128 + ch);
      ushort2 u3 = *(const ushort2*)(hin + (size_t)s3 * 128 + ch);
      acc0 += q0 * bf2f(u0.x); acc1 += q0 * bf2f(u0.y);
      acc0 += q1 * bf2f(u1.x); acc1 += q1 * bf2f(u1.y);
      acc0 += q2 * bf2f(u2.x); acc1 += q2 * bf2f(u2.y);
      acc0 += q3 * bf2f(u3.x); acc1 += q3 * bf2f(u3.y);
    }
    for (; k < len; ++k) {
      int s = sbuf[wv][k];
      float q = pbuf[wv][k * 4 + head];
      ushort2 u = *(const ushort2*)(hin + (size_t)s * 128 + ch);
      acc0 += q * bf2f(u.x); acc1 += q * bf2f(u.y);
    }
  }

#pragma unroll
  for (int off = 32; off; off >>= 1) {
    sa.x += __shfl_xor(sa.x, off);
    sa.y += __shfl_xor(sa.y, off);
    sa.z += __shfl_xor(sa.z, off);
    sa.w += __shfl_xor(sa.w, off);
  }
  const int deg = j1 - j0;
  const float invd = 1.f / fmaxf((float)deg, 1.f);
  const float4 sn = *(const float4*)(ssc + (size_t)node * 4);
  float4 al;
  al.x = leaky02(sn.x + dv.x + sa.x * invd);
  al.y = leaky02(sn.y + dv.y + sa.y * invd);
  al.z = leaky02(sn.z + dv.z + sa.z * invd);
  al.w = leaky02(sn.w + dv.w + sa.w * invd);
  float4 mn = make_float4(fmaxf(m4.x, al.x), fmaxf(m4.y, al.y),
                          fmaxf(m4.z, al.z), fmaxf(m4.w, al.w));
  float4 sc, p4;
  sc.x = __expf(m4.x - mn.x); p4.x = __expf(al.x - mn.x);
  sc.y = __expf(m4.y - mn.y); p4.y = __expf(al.y - mn.y);
  sc.z = __expf(m4.z - mn.z); p4.z = __expf(al.z - mn.z);
  sc.w = __expf(m4.w - mn.w); p4.w = __expf(al.w - mn.w);
  const float sch = sel4(sc, head);
  const float ph = sel4(p4, head);
  ushort2 uh = *(const ushort2*)(hin + (size_t)node * 128 + ch);
  acc0 = acc0 * sch + ph * bf2f(uh.x);
  acc1 = acc1 * sch + ph * bf2f(uh.y);
  l4.x = l4.x * sc.x + p4.x;
  l4.y = l4.y * sc.y + p4.y;
  l4.z = l4.z * sc.z + p4.z;
  l4.w = l4.w * sc.w + p4.w;
  const float invl = 1.f / (sel4(l4, head) + 1e-16f);
  float o0 = acc0 * invl + bias[ch];
  float o1 = acc1 * invl + bias[ch + 1];
  ushort2 o; o.x = f2bf(fmaxf(o0, 0.f)); o.y = f2bf(fmaxf(o1, 0.f));
  *(ushort2*)(hout + (size_t)node * 128 + ch) = o;
}

// logits = h @ Wlin.T + blin; log_softmax over 40 classes. one wave per node.
__global__ __launch_bounds__(256) void classifier_kernel(const unsigned short* __restrict__ h,
                                                         const float* __restrict__ Wlin,
                                                         const float* __restrict__ blin,
                                                         float* __restrict__ out, int n) {
  __shared__ float wt[128 * 40];
  __shared__ float hs[4][128];
  for (int idx = threadIdx.x; idx < 40 * 128; idx += 256) {
    int c = idx >> 7, k = idx & 127;
    wt[k * 40 + c] = Wlin[idx];
  }
  int w = threadIdx.x >> 6, lane = threadIdx.x & 63;
  int node = blockIdx.x * 4 + w;
  if (node < n) {
    hs[w][lane] = bf2f(h[(size_t)node * 128 + lane]);
    hs[w][lane + 64] = bf2f(h[(size_t)node * 128 + lane + 64]);
  }
  __syncthreads();
  if (node >= n) return;
  float logit = -INFINITY;
  if (lane < 40) {
    float acc = blin[lane];
#pragma unroll 4
    for (int k = 0; k < 128; ++k) acc += hs[w][k] * wt[k * 40 + lane];
    logit = acc;
  }
  float mx = logit;
#pragma unroll
  for (int off = 32; off; off >>= 1) mx = fmaxf(mx, __shfl_xor(mx, off));
  float ex = (lane < 40) ? __expf(logit - mx) : 0.f;
  float sm = ex;
#pragma unroll
  for (int off = 32; off; off >>= 1) sm += __shfl_xor(sm, off);
  if (lane < 40) out[(size_t)node * 40 + lane] = logit - mx - __logf(sm);
}

extern "C" void kernel_launch(void* const* d_in, const int* in_sizes, int n_in,
                              void* d_out, int out_size, void* d_ws, size_t ws_size,
                              hipStream_t stream) {
  const float* x    = (const float*)d_in[0];
  const int*   eidx = (const int*)d_in[1];
  const float* ea   = (const float*)d_in[2];
  const float* W1   = (const float*)d_in[3];
  const float* as1  = (const float*)d_in[4];
  const float* ad1  = (const float*)d_in[5];
  const float* ae1w = (const float*)d_in[6];
  const float* We1  = (const float*)d_in[7];
  const float* b1   = (const float*)d_in[8];
  const float* W2   = (const float*)d_in[9];
  const float* as2  = (const float*)d_in[10];
  const float* ad2  = (const float*)d_in[11];
  const float* ae2w = (const float*)d_in[12];
  const float* We2  = (const float*)d_in[13];
  const float* b2   = (const float*)d_in[14];
  const float* Wlin = (const float*)d_in[15];
  const float* blin = (const float*)d_in[16];
  float* out = (float*)d_out;

  const int N = in_sizes[0] / 64;
  const int E = in_sizes[1] / 2;
  const int* src = eidx;
  const int* dst = eidx + E;
  const int NB = (N + 127) >> 7;  // 391 for N=50000 (must be <= 512)

  char* wsb = (char*)d_ws;
  size_t off = 0;
  auto alloc = [&](size_t bytes) -> void* {
    void* p = wsb + off;
    off = (off + bytes + 255) & ~(size_t)255;
    return p;
  };
  int* bucketCnt  = (int*)alloc(512 * 4);
  int* bucketOffs = (int*)alloc(513 * 4);
  int* bucketPos  = (int*)alloc(512 * 4);
  int* offs       = (int*)alloc((size_t)(N + 1) * 4);
  // binned (int2, E) aliases hA (bf16 N*128): binned dead after passC, hA born at gemm1
  void* bhA       = alloc((size_t)E * 8 > (size_t)N * 256 ? (size_t)E * 8 : (size_t)N * 256);
  int2* binned    = (int2*)bhA;
  unsigned short* hA = (unsigned short*)bhA;
  int* srcS       = (int*)alloc((size_t)E * 4);
  int* elist      = (int*)alloc((size_t)E * 4);
  float* Wa       = (float*)alloc(128 * 4);
  unsigned short* xb  = (unsigned short*)alloc((size_t)N * 64 * 2);
  unsigned short* Wb1 = (unsigned short*)alloc(128 * 64 * 2);
  unsigned short* Wb2 = (unsigned short*)alloc(128 * 128 * 2);
  float* ssc      = (float*)alloc((size_t)N * 4 * 4);
  float* dsc      = (float*)alloc((size_t)N * 4 * 4);
  unsigned short* ae12 = (unsigned short*)alloc((size_t)E * 8 * 2);
  unsigned short* hB   = (unsigned short*)alloc((size_t)N * 128 * 2);

  const int ge = (E + 255) / 256;
  const int gg = (N + 63) / 64;
  const int gn = (N + 3) / 4;
  const int gp = (E + CHUNK - 1) / CHUNK;

  // ---- CSR build via bucket sort ----
  hipMemsetAsync(bucketCnt, 0, 512 * 4, stream);
  hist_kernel<<<gp, 512, 0, stream>>>(dst, bucketCnt, E, NB);
  scanB_kernel<<<1, 512, 0, stream>>>(bucketCnt, bucketOffs, bucketPos, offs, NB, N, E);
  partB_kernel<<<gp, 512, 0, stream>>>(src, dst, bucketPos, binned, E, NB);
  passC_kernel<<<NB, 256, 0, stream>>>(binned, bucketOffs, srcS, elist, offs, N);

  wa_kernel<<<1, 128, 0, stream>>>(ae1w, We1, ae2w, We2, Wa);
  cvt_kernel<<<(N * 64 + 255) / 256, 256, 0, stream>>>(x, xb, N * 64);
  cvt_kernel<<<(128 * 64 + 255) / 256, 256, 0, stream>>>(W1, Wb1, 128 * 64);
  cvt_kernel<<<(128 * 128 + 255) / 256, 256, 0, stream>>>(W2, Wb2, 128 * 128);
  alphae12_kernel<<<ge, 256, 0, stream>>>(elist, ea, Wa, ae12, E);

  // ---- layer 1 ----
  gemm_mfma_kernel<<<gg, 256, 0, stream>>>(xb, Wb1, hA, N, 64);
  score_kernel<<<gn, 256, 0, stream>>>(hA, as1, ad1, ssc, dsc, N);
  agg_kernel<<<gn, 256, 0, stream>>>(hA, ssc, dsc, ae12, 0, offs, srcS, b1, hB, N);

  // ---- layer 2 ----
  gemm_mfma_kernel<<<gg, 256, 0, stream>>>(hB, Wb2, hA, N, 128);
  score_kernel<<<gn, 256, 0, stream>>>(hA, as2, ad2, ssc, dsc, N);
  agg_kernel<<<gn, 256, 0, stream>>>(hA, ssc, dsc, ae12, 4, offs, srcS, b2, hB, N);

  // ---- classifier + log_softmax ----
  classifier_kernel<<<gn, 256, 0, stream>>>(hB, Wlin, blin, out, N);
}